// Round 5
// baseline (413.654 us; speedup 1.0000x reference)
//
#include <hip/hip_runtime.h>

#define NB 100000
#define NC 10000
#define NT 1000
#define EADJ 800000
#define EB2C 100000
#define EC2T 10000

// block counts for the merged hierarchical scan (tile = 2048)
#define SBA 49   // ceil(NB/2048)
#define SBB 5    // ceil(NC/2048)
#define SBC 1    // ceil(NT/2048)

// ---------- types ----------
typedef __bf16 bf16x8 __attribute__((ext_vector_type(8)));
typedef short  s16x8  __attribute__((ext_vector_type(8)));
typedef float  f32x4  __attribute__((ext_vector_type(4)));

union frag_u { s16x8 s; bf16x8 b; };

__device__ __forceinline__ unsigned short f2b(float f) {
  unsigned u = __float_as_uint(f);
  u = (u + 0x7fffu + ((u >> 16) & 1u)) >> 16;   // RNE to bf16
  return (unsigned short)u;
}
__device__ __forceinline__ float b2f(unsigned short u) {
  return __uint_as_float(((unsigned)u) << 16);
}

// ================= CSR build (merged across 3 edge sets) =================

__global__ __launch_bounds__(256) void deg_count_all(const int* __restrict__ ea,
                                                     const int* __restrict__ eb,
                                                     const int* __restrict__ ec,
                                                     int* __restrict__ da,
                                                     int* __restrict__ db,
                                                     int* __restrict__ dc) {
  int t = blockIdx.x * 256 + threadIdx.x;
  if (t < EADJ) {
    atomicAdd(&da[ea[EADJ + t]], 1);
  } else if (t < EADJ + EB2C) {
    int e = t - EADJ;
    atomicAdd(&db[eb[EB2C + e]], 1);
  } else if (t < EADJ + EB2C + EC2T) {
    int e = t - EADJ - EB2C;
    atomicAdd(&dc[ec[EC2T + e]], 1);
  }
}

__global__ __launch_bounds__(256) void scan_bsum_all(const int* __restrict__ da,
                                                     const int* __restrict__ db,
                                                     const int* __restrict__ dc,
                                                     int* __restrict__ bs) {
  const int* deg; int N, lb; int* out;
  int b = blockIdx.x;
  if (b < SBA)            { deg = da; N = NB; lb = b;            out = bs; }
  else if (b < SBA + SBB) { deg = db; N = NC; lb = b - SBA;      out = bs + SBA; }
  else                    { deg = dc; N = NT; lb = 0;            out = bs + SBA + SBB; }
  __shared__ int red[256];
  int t = threadIdx.x;
  int base = lb * 2048 + t * 8;
  int s = 0;
  if (base + 8 <= N) {
    int4 a = *(const int4*)(deg + base);
    int4 c = *(const int4*)(deg + base + 4);
    s = a.x + a.y + a.z + a.w + c.x + c.y + c.z + c.w;
  } else {
#pragma unroll
    for (int i = 0; i < 8; i++) { int idx = base + i; if (idx < N) s += deg[idx]; }
  }
  red[t] = s;
  __syncthreads();
  for (int off = 128; off >= 1; off >>= 1) {
    if (t < off) red[t] += red[t + off];
    __syncthreads();
  }
  if (t == 0) out[lb] = red[0];
}

__global__ __launch_bounds__(256) void scan_excl_all(int* __restrict__ bs) {
  int* p; int n;
  if (blockIdx.x == 0)      { p = bs;             n = SBA; }
  else if (blockIdx.x == 1) { p = bs + SBA;       n = SBB; }
  else                      { p = bs + SBA + SBB; n = SBC; }
  __shared__ int sh[256];
  int t = threadIdx.x;
  sh[t] = (t < n) ? p[t] : 0;
  __syncthreads();
  for (int off = 1; off < 256; off <<= 1) {
    int v = (t >= off) ? sh[t - off] : 0;
    __syncthreads();
    sh[t] += v;
    __syncthreads();
  }
  if (t < n) p[t] = (t == 0) ? 0 : sh[t - 1];
}

__global__ __launch_bounds__(256) void scan_write_all(const int* __restrict__ da,
                                                      const int* __restrict__ db,
                                                      const int* __restrict__ dc,
                                                      const int* __restrict__ bs,
                                                      int* __restrict__ rp_a, int* __restrict__ cur_a,
                                                      int* __restrict__ rp_b, int* __restrict__ cur_b,
                                                      int* __restrict__ rp_c, int* __restrict__ cur_c,
                                                      float* __restrict__ dinv) {
  const int* deg; int N, lb; const int* bsum; int* rp; int* cur; bool dodinv = false;
  int b = blockIdx.x;
  if (b < SBA)            { deg = da; N = NB; lb = b;       bsum = bs;             rp = rp_a; cur = cur_a; dodinv = true; }
  else if (b < SBA + SBB) { deg = db; N = NC; lb = b - SBA; bsum = bs + SBA;       rp = rp_b; cur = cur_b; }
  else                    { deg = dc; N = NT; lb = 0;       bsum = bs + SBA + SBB; rp = rp_c; cur = cur_c; }
  __shared__ int sh[256];
  int t = threadIdx.x;
  int base = lb * 2048 + t * 8;
  int d[8]; int s = 0;
#pragma unroll
  for (int i = 0; i < 8; i++) { int idx = base + i; d[i] = (idx < N) ? deg[idx] : 0; s += d[i]; }
  sh[t] = s;
  __syncthreads();
  for (int off = 1; off < 256; off <<= 1) {
    int v = (t >= off) ? sh[t - off] : 0;
    __syncthreads();
    sh[t] += v;
    __syncthreads();
  }
  int run = bsum[lb] + ((t == 0) ? 0 : sh[t - 1]);
#pragma unroll
  for (int i = 0; i < 8; i++) {
    int idx = base + i;
    if (idx < N) {
      rp[idx] = run;
      cur[idx] = run;
      run += d[i];
      if (idx == N - 1) rp[N] = run;
      if (dodinv) dinv[idx] = rsqrtf((float)(d[i] + 1));   // +1 self-loop
    }
  }
}

__global__ __launch_bounds__(256) void csr_fill_all(const int* __restrict__ ea,
                                                    const int* __restrict__ eb,
                                                    const int* __restrict__ ec,
                                                    int* __restrict__ cur_a, int* __restrict__ cur_b, int* __restrict__ cur_c,
                                                    int* __restrict__ col_a, int* __restrict__ col_b, int* __restrict__ col_c) {
  int t = blockIdx.x * 256 + threadIdx.x;
  if (t < EADJ) {
    int src = ea[t], dst = ea[EADJ + t];
    col_a[atomicAdd(&cur_a[dst], 1)] = src;
  } else if (t < EADJ + EB2C) {
    int e = t - EADJ;
    int src = eb[e], dst = eb[EB2C + e];
    col_b[atomicAdd(&cur_b[dst], 1)] = src;
  } else if (t < EADJ + EB2C + EC2T) {
    int e = t - EADJ - EB2C;
    int src = ec[e], dst = ec[EC2T + e];
    col_c[atomicAdd(&cur_c[dst], 1)] = src;
  }
}

// ================= attention-weight folding =================
// wt[mat][k*4+h] = sum_c W[k, h*32+c] * att[h,c]
__global__ __launch_bounds__(256) void prep_watt(const float* __restrict__ W0, const float* __restrict__ A0,
                                                 const float* __restrict__ W1, const float* __restrict__ A1,
                                                 const float* __restrict__ W2, const float* __restrict__ A2,
                                                 const float* __restrict__ W3, const float* __restrict__ A3,
                                                 float* __restrict__ wt) {
  const float* Ws[4] = {W0, W1, W2, W3};
  const float* As[4] = {A0, A1, A2, A3};
  int t = threadIdx.x;
#pragma unroll
  for (int mm = 0; mm < 4; mm++) {
#pragma unroll
    for (int r = 0; r < 2; r++) {
      int idx = r * 256 + t;
      int k = idx >> 2, h = idx & 3;
      float s = 0.f;
      for (int c = 0; c < 32; c++) s += Ws[mm][k * 128 + h * 32 + c] * As[mm][h * 32 + c];
      wt[mm * 512 + k * 4 + h] = s;
    }
  }
}

// Pre-convert weights to bf16 in B-operand layout (transposed): bt[n*128+k] = bf16(W[k*128+n]).
// Block 3 builds the two zero-padded w̃ tiles (16x128 each): wtb[seg][n*128+k].
__global__ __launch_bounds__(256) void conv_w(const float* __restrict__ W1,
                                              const float* __restrict__ W2,
                                              const float* __restrict__ W3,
                                              const float* __restrict__ wt,
                                              unsigned short* __restrict__ bt1,
                                              unsigned short* __restrict__ bt2,
                                              unsigned short* __restrict__ bt3,
                                              unsigned short* __restrict__ wtb) {
  int b = blockIdx.x, t = threadIdx.x;
  if (b < 3) {
    const float* W = (b == 0) ? W1 : (b == 1) ? W2 : W3;
    unsigned short* bt = (b == 0) ? bt1 : (b == 1) ? bt2 : bt3;
#pragma unroll
    for (int i = 0; i < 16; i++) {
      int flat4 = i * 256 + t;
      int k = flat4 >> 5;
      int n0 = (flat4 & 31) * 4;
      float4 v = *(const float4*)(W + k * 128 + n0);
      bt[(n0 + 0) * 128 + k] = f2b(v.x);
      bt[(n0 + 1) * 128 + k] = f2b(v.y);
      bt[(n0 + 2) * 128 + k] = f2b(v.z);
      bt[(n0 + 3) * 128 + k] = f2b(v.w);
    }
  } else {
#pragma unroll
    for (int i = 0; i < 16; i++) {
      int idx = i * 256 + t;              // 0..4095: seg0 = b2c_src w̃, seg1 = c2t_src w̃
      int seg = idx >> 11, r = idx & 2047;
      int n = r >> 7, k = r & 127;
      const float* ws = wt + seg * 1024;  // wt seg 0 and seg 2
      wtb[seg * 2048 + n * 128 + k] = (n < 4) ? f2b(ws[k * 4 + n]) : (unsigned short)0;
    }
  }
}

// a_d for cable and transformer nodes: one wave per node
__global__ __launch_bounds__(256) void small_ad(const float* __restrict__ x_c,
                                                const float* __restrict__ x_t,
                                                const float* __restrict__ wt,
                                                float* __restrict__ a_d_c,
                                                float* __restrict__ a_d_t) {
  int widx = blockIdx.x * 4 + (threadIdx.x >> 6);
  int lane = threadIdx.x & 63;
  const float* x; const float* w; float* out;
  if (widx < NC)            { x = x_c + (size_t)widx * 128;        w = wt + 512;  out = a_d_c + widx * 4; }
  else if (widx < NC + NT)  { int n = widx - NC; x = x_t + (size_t)n * 128; w = wt + 1536; out = a_d_t + n * 4; }
  else return;
  float2 xv = ((const float2*)x)[lane];
  float p[4];
#pragma unroll
  for (int h = 0; h < 4; h++)
    p[h] = xv.x * w[(2 * lane) * 4 + h] + xv.y * w[(2 * lane + 1) * 4 + h];
#pragma unroll
  for (int off = 32; off >= 1; off >>= 1)
#pragma unroll
    for (int h = 0; h < 4; h++) p[h] += __shfl_xor(p[h], off);
  if (lane == 0) *(float4*)out = (float4){p[0], p[1], p[2], p[3]};
}

// ================= fused GEMMs (zero-LDS; B operands from global/L2) =================
// 64 rows/block (16 rows/wave). xs = bf16(X@W1), hgs = bf16(dinv*(X@W2)), a_s via w̃ tile.
__global__ __launch_bounds__(256) void gemm_dual(const float* __restrict__ X,
                                                 const unsigned short* __restrict__ bt1,
                                                 const unsigned short* __restrict__ bt2,
                                                 const unsigned short* __restrict__ wtb,
                                                 const float* __restrict__ dinv,
                                                 unsigned short* __restrict__ xs_out,
                                                 unsigned short* __restrict__ hg_out,
                                                 float* __restrict__ as_out, int M) {
  const int tid = threadIdx.x;
  const int lane = tid & 63;
  const int wave = tid >> 6;
  const int m = lane & 15, q = lane >> 4;

  int r0 = blockIdx.x * 64 + wave * 16 + m;
  if (r0 >= M) r0 = M - 1;
  const float* xr = X + (size_t)r0 * 128;

  f32x4 acc1[8], acc2[8], accw;
  accw = (f32x4){0.f, 0.f, 0.f, 0.f};
#pragma unroll
  for (int ct = 0; ct < 8; ct++) {
    acc1[ct] = (f32x4){0.f, 0.f, 0.f, 0.f};
    acc2[ct] = (f32x4){0.f, 0.f, 0.f, 0.f};
  }

#pragma unroll
  for (int ks = 0; ks < 4; ks++) {
    const int ko = ks * 32 + q * 8;
    const float* p = xr + ko;
    float4 v0 = *(const float4*)p;
    float4 v1 = *(const float4*)(p + 4);
    frag_u a;
    a.s = (s16x8){(short)f2b(v0.x), (short)f2b(v0.y), (short)f2b(v0.z), (short)f2b(v0.w),
                  (short)f2b(v1.x), (short)f2b(v1.y), (short)f2b(v1.z), (short)f2b(v1.w)};
    frag_u bw;
    bw.s = *(const s16x8*)(wtb + m * 128 + ko);
    accw = __builtin_amdgcn_mfma_f32_16x16x32_bf16(a.b, bw.b, accw, 0, 0, 0);
#pragma unroll
    for (int ct = 0; ct < 8; ct++) {
      frag_u b1, b2;
      b1.s = *(const s16x8*)(bt1 + (ct * 16 + m) * 128 + ko);
      b2.s = *(const s16x8*)(bt2 + (ct * 16 + m) * 128 + ko);
      acc1[ct] = __builtin_amdgcn_mfma_f32_16x16x32_bf16(a.b, b1.b, acc1[ct], 0, 0, 0);
      acc2[ct] = __builtin_amdgcn_mfma_f32_16x16x32_bf16(a.b, b2.b, acc2[ct], 0, 0, 0);
    }
  }

  // C/D layout: col = lane&15 (=m), row = q*4 + reg
#pragma unroll
  for (int i = 0; i < 4; i++) {
    int r = blockIdx.x * 64 + wave * 16 + q * 4 + i;
    if (r < M) {
      float dd = dinv[r];
      unsigned short* xp = xs_out + (size_t)r * 128 + m;
      unsigned short* hp = hg_out + (size_t)r * 128 + m;
#pragma unroll
      for (int ct = 0; ct < 8; ct++) {
        xp[ct * 16] = f2b(acc1[ct][i]);
        hp[ct * 16] = f2b(dd * acc2[ct][i]);
      }
      if (m < 4) as_out[(size_t)r * 4 + m] = accw[i];
    }
  }
}

__global__ __launch_bounds__(256) void gemm_single(const float* __restrict__ X,
                                                   const unsigned short* __restrict__ bt1,
                                                   const unsigned short* __restrict__ wtb,
                                                   unsigned short* __restrict__ xs_out,
                                                   float* __restrict__ as_out, int M) {
  const int tid = threadIdx.x;
  const int lane = tid & 63;
  const int wave = tid >> 6;
  const int m = lane & 15, q = lane >> 4;

  int r0 = blockIdx.x * 64 + wave * 16 + m;
  if (r0 >= M) r0 = M - 1;
  const float* xr = X + (size_t)r0 * 128;

  f32x4 acc1[8], accw;
  accw = (f32x4){0.f, 0.f, 0.f, 0.f};
#pragma unroll
  for (int ct = 0; ct < 8; ct++) acc1[ct] = (f32x4){0.f, 0.f, 0.f, 0.f};

#pragma unroll
  for (int ks = 0; ks < 4; ks++) {
    const int ko = ks * 32 + q * 8;
    const float* p = xr + ko;
    float4 v0 = *(const float4*)p;
    float4 v1 = *(const float4*)(p + 4);
    frag_u a;
    a.s = (s16x8){(short)f2b(v0.x), (short)f2b(v0.y), (short)f2b(v0.z), (short)f2b(v0.w),
                  (short)f2b(v1.x), (short)f2b(v1.y), (short)f2b(v1.z), (short)f2b(v1.w)};
    frag_u bw;
    bw.s = *(const s16x8*)(wtb + m * 128 + ko);
    accw = __builtin_amdgcn_mfma_f32_16x16x32_bf16(a.b, bw.b, accw, 0, 0, 0);
#pragma unroll
    for (int ct = 0; ct < 8; ct++) {
      frag_u b1;
      b1.s = *(const s16x8*)(bt1 + (ct * 16 + m) * 128 + ko);
      acc1[ct] = __builtin_amdgcn_mfma_f32_16x16x32_bf16(a.b, b1.b, acc1[ct], 0, 0, 0);
    }
  }

#pragma unroll
  for (int i = 0; i < 4; i++) {
    int r = blockIdx.x * 64 + wave * 16 + q * 4 + i;
    if (r < M) {
      unsigned short* xp = xs_out + (size_t)r * 128 + m;
#pragma unroll
      for (int ct = 0; ct < 8; ct++) xp[ct * 16] = f2b(acc1[ct][i]);
      if (m < 4) as_out[(size_t)r * 4 + m] = accw[i];
    }
  }
}

// ================= gathers =================

__global__ __launch_bounds__(256) void gat_gather(const int* __restrict__ rowptr,
                                                  const int* __restrict__ col,
                                                  const float* __restrict__ a_s,
                                                  const float* __restrict__ a_d,
                                                  const unsigned short* __restrict__ xs,
                                                  const float* __restrict__ xd_in,
                                                  const float* __restrict__ bias,
                                                  float* __restrict__ out, int Nd, float s) {
  int node = blockIdx.x * 8 + (threadIdx.x >> 5);
  if (node >= Nd) return;
  int g = threadIdx.x & 31;
  int c4 = g * 4, h = g >> 3;
  int lo = rowptr[node], hi = rowptr[node + 1];
  float ad = a_d[(size_t)node * 4 + h];
  float4 acc = {0.f, 0.f, 0.f, 0.f};
  float sexp = 0.f;
  int j = lo;
  for (; j + 1 < hi; j += 2) {
    int s0 = col[j], s1 = col[j + 1];
    float l0 = a_s[(size_t)s0 * 4 + h] + ad;
    float l1 = a_s[(size_t)s1 * 4 + h] + ad;
    ushort4 u0 = *(const ushort4*)(xs + (size_t)s0 * 128 + c4);
    ushort4 u1 = *(const ushort4*)(xs + (size_t)s1 * 128 + c4);
    l0 = l0 > 0.f ? l0 : 0.2f * l0;
    l1 = l1 > 0.f ? l1 : 0.2f * l1;
    float w0 = __expf(l0), w1 = __expf(l1);
    sexp += w0 + w1;
    acc.x += w0 * b2f(u0.x) + w1 * b2f(u1.x);
    acc.y += w0 * b2f(u0.y) + w1 * b2f(u1.y);
    acc.z += w0 * b2f(u0.z) + w1 * b2f(u1.z);
    acc.w += w0 * b2f(u0.w) + w1 * b2f(u1.w);
  }
  if (j < hi) {
    int s0 = col[j];
    float l0 = a_s[(size_t)s0 * 4 + h] + ad;
    ushort4 u0 = *(const ushort4*)(xs + (size_t)s0 * 128 + c4);
    l0 = l0 > 0.f ? l0 : 0.2f * l0;
    float w0 = __expf(l0);
    sexp += w0;
    acc.x += w0 * b2f(u0.x);
    acc.y += w0 * b2f(u0.y);
    acc.z += w0 * b2f(u0.z);
    acc.w += w0 * b2f(u0.w);
  }
  float inv = s / (sexp + 1e-16f);
  float4 xd = *(const float4*)(xd_in + (size_t)node * 128 + c4);
  float4 bv = *(const float4*)(bias + c4);
  float4 r = {xd.x + s * bv.x + inv * acc.x, xd.y + s * bv.y + inv * acc.y,
              xd.z + s * bv.z + inv * acc.z, xd.w + s * bv.w + inv * acc.w};
  *(float4*)(out + (size_t)node * 128 + c4) = r;
}

// GCN gather: hgs rows pre-scaled by dinv[src]; self row folded in; unroll x4.
__global__ __launch_bounds__(256) void gcn_gather(const int* __restrict__ rowptr,
                                                  const int* __restrict__ col,
                                                  const unsigned short* __restrict__ hgs,
                                                  const float* __restrict__ dinv,
                                                  const float* __restrict__ x,
                                                  const float* __restrict__ bias,
                                                  float* __restrict__ out, int N, float s) {
  int node = blockIdx.x * 8 + (threadIdx.x >> 5);
  if (node >= N) return;
  int c4 = (threadIdx.x & 31) * 4;
  int lo = rowptr[node], hi = rowptr[node + 1];
  ushort4 su = *(const ushort4*)(hgs + (size_t)node * 128 + c4);
  float4 acc = {b2f(su.x), b2f(su.y), b2f(su.z), b2f(su.w)};
  int j = lo;
  for (; j + 3 < hi; j += 4) {
    int s0 = col[j], s1 = col[j + 1], s2 = col[j + 2], s3 = col[j + 3];
    ushort4 u0 = *(const ushort4*)(hgs + (size_t)s0 * 128 + c4);
    ushort4 u1 = *(const ushort4*)(hgs + (size_t)s1 * 128 + c4);
    ushort4 u2 = *(const ushort4*)(hgs + (size_t)s2 * 128 + c4);
    ushort4 u3 = *(const ushort4*)(hgs + (size_t)s3 * 128 + c4);
    acc.x += (b2f(u0.x) + b2f(u1.x)) + (b2f(u2.x) + b2f(u3.x));
    acc.y += (b2f(u0.y) + b2f(u1.y)) + (b2f(u2.y) + b2f(u3.y));
    acc.z += (b2f(u0.z) + b2f(u1.z)) + (b2f(u2.z) + b2f(u3.z));
    acc.w += (b2f(u0.w) + b2f(u1.w)) + (b2f(u2.w) + b2f(u3.w));
  }
  for (; j < hi; j++) {
    int s0 = col[j];
    ushort4 u0 = *(const ushort4*)(hgs + (size_t)s0 * 128 + c4);
    acc.x += b2f(u0.x); acc.y += b2f(u0.y); acc.z += b2f(u0.z); acc.w += b2f(u0.w);
  }
  float dd = dinv[node];
  float4 xv = *(const float4*)(x + (size_t)node * 128 + c4);
  float4 bv = *(const float4*)(bias + c4);
  float4 r = {xv.x + s * (dd * acc.x + bv.x), xv.y + s * (dd * acc.y + bv.y),
              xv.z + s * (dd * acc.z + bv.z), xv.w + s * (dd * acc.w + bv.w)};
  *(float4*)(out + (size_t)node * 128 + c4) = r;
}

// ================= host =================
extern "C" void kernel_launch(void* const* d_in, const int* in_sizes, int n_in,
                              void* d_out, int out_size, void* d_ws, size_t ws_size,
                              hipStream_t stream) {
  const float* x_b        = (const float*)d_in[0];
  const float* x_c        = (const float*)d_in[1];
  const float* x_t        = (const float*)d_in[2];
  const int*   e_b2c      = (const int*)d_in[3];
  const int*   e_c2t      = (const int*)d_in[4];
  const int*   e_adj      = (const int*)d_in[5];
  const float* W_b2c_src  = (const float*)d_in[6];
  const float* W_b2c_dst  = (const float*)d_in[7];
  const float* att_b2c_s  = (const float*)d_in[8];
  const float* att_b2c_d  = (const float*)d_in[9];
  const float* b_b2c      = (const float*)d_in[10];
  const float* W_c2t_src  = (const float*)d_in[11];
  const float* W_c2t_dst  = (const float*)d_in[12];
  const float* att_c2t_s  = (const float*)d_in[13];
  const float* att_c2t_d  = (const float*)d_in[14];
  const float* b_c2t      = (const float*)d_in[15];
  const float* W_gcn      = (const float*)d_in[16];
  const float* b_gcn      = (const float*)d_in[17];

  float* h_b = (float*)d_out;
  float* h_c = h_b + (size_t)NB * 128;
  float* h_t = h_c + (size_t)NC * 128;

  char* w = (char*)d_ws;
  auto allocu = [&](size_t n) { unsigned short* p = (unsigned short*)w; w += n * 2; return p; };
  auto allocf = [&](size_t n) { float* p = (float*)w; w += n * 4; return p; };
  auto alloci = [&](size_t n) { int* p = (int*)w; w += n * 4; return p; };

  unsigned short* xs_b = allocu((size_t)NB * 128);   // bf16 payloads
  unsigned short* hgs  = allocu((size_t)NB * 128);   // bf16, dinv-pre-scaled
  unsigned short* xs_c = allocu((size_t)NC * 128);
  unsigned short* bt1  = allocu(128 * 128);          // bf16 W_b2c_src^T
  unsigned short* bt2  = allocu(128 * 128);          // bf16 W_gcn^T
  unsigned short* bt3  = allocu(128 * 128);          // bf16 W_c2t_src^T
  unsigned short* wtb  = allocu(2 * 2048);           // two 16x128 w̃ tiles
  float* a_d_c = allocf((size_t)NC * 4);
  float* a_d_t = allocf((size_t)NT * 4);
  float* a_s_b = allocf((size_t)NB * 4);
  float* a_s_c = allocf((size_t)NC * 4);
  float* dinv  = allocf(NB);
  float* wt    = allocf(4 * 512);
  int* deg_a = alloci(NB);   // deg_a..deg_c contiguous for one memset
  int* deg_b = alloci(NC);
  int* deg_c = alloci(NT);
  int* bs    = alloci(64);
  int* rp_a  = alloci(NB + 1);  int* cur_a = alloci(NB);  int* col_a = alloci(EADJ);
  int* rp_b  = alloci(NC + 1);  int* cur_b = alloci(NC);  int* col_b = alloci(EB2C);
  int* rp_c  = alloci(NT + 1);  int* cur_c = alloci(NT);  int* col_c = alloci(EC2T);

  const int ETOT = EADJ + EB2C + EC2T;

  // ---- CSR build (merged) ----
  hipMemsetAsync(deg_a, 0, (size_t)(NB + NC + NT) * sizeof(int), stream);
  deg_count_all<<<(ETOT + 255) / 256, 256, 0, stream>>>(e_adj, e_b2c, e_c2t, deg_a, deg_b, deg_c);
  scan_bsum_all<<<SBA + SBB + SBC, 256, 0, stream>>>(deg_a, deg_b, deg_c, bs);
  scan_excl_all<<<3, 256, 0, stream>>>(bs);
  scan_write_all<<<SBA + SBB + SBC, 256, 0, stream>>>(deg_a, deg_b, deg_c, bs,
                                                      rp_a, cur_a, rp_b, cur_b, rp_c, cur_c, dinv);
  csr_fill_all<<<(ETOT + 255) / 256, 256, 0, stream>>>(e_adj, e_b2c, e_c2t,
                                                       cur_a, cur_b, cur_c, col_a, col_b, col_c);

  // ---- weight prep ----
  prep_watt<<<1, 256, 0, stream>>>(W_b2c_src, att_b2c_s, W_b2c_dst, att_b2c_d,
                                   W_c2t_src, att_c2t_s, W_c2t_dst, att_c2t_d, wt);
  conv_w<<<4, 256, 0, stream>>>(W_b2c_src, W_gcn, W_c2t_src, wt, bt1, bt2, bt3, wtb);
  small_ad<<<(NC + NT + 3) / 4, 256, 0, stream>>>(x_c, x_t, wt, a_d_c, a_d_t);

  // ---- big fused GEMM: x_b -> xs_b, hgs (dinv-scaled), a_s_b ----
  gemm_dual<<<(NB + 63) / 64, 256, 0, stream>>>(x_b, bt1, bt2, wtb, dinv,
                                                xs_b, hgs, a_s_b, NB);

  // ---- stage A: building -> cable_group GAT ----
  gat_gather<<<(NC + 7) / 8, 256, 0, stream>>>(rp_b, col_b, a_s_b, a_d_c,
                                               xs_b, x_c, b_b2c, h_c, NC, 0.5f);

  // ---- stage B: cable_group -> transformer GAT ----
  gemm_single<<<(NC + 63) / 64, 256, 0, stream>>>(h_c, bt3, wtb + 2048, xs_c, a_s_c, NC);
  gat_gather<<<(NT + 7) / 8, 256, 0, stream>>>(rp_c, col_c, a_s_c, a_d_t,
                                               xs_c, x_t, b_c2t, h_t, NT, 0.5f);

  // ---- GCN on building adjacency ----
  gcn_gather<<<(NB + 7) / 8, 256, 0, stream>>>(rp_a, col_a, hgs, dinv, x_b, b_gcn, h_b, NB, 0.2f);
}

// Round 6
// 363.482 us; speedup vs baseline: 1.1380x; 1.1380x over previous
//
#include <hip/hip_runtime.h>

#define NB 100000
#define NC 10000
#define NT 1000
#define EADJ 800000
#define EB2C 100000
#define EC2T 10000

// block counts for the merged hierarchical scan (tile = 2048)
#define SBA 49   // ceil(NB/2048)
#define SBB 5    // ceil(NC/2048)
#define SBC 1    // ceil(NT/2048)

// ---------- types ----------
typedef __bf16 bf16x8 __attribute__((ext_vector_type(8)));
typedef short  s16x8  __attribute__((ext_vector_type(8)));
typedef float  f32x4  __attribute__((ext_vector_type(4)));

union frag_u { s16x8 s; bf16x8 b; };

__device__ __forceinline__ unsigned short f2b(float f) {
  unsigned u = __float_as_uint(f);
  u = (u + 0x7fffu + ((u >> 16) & 1u)) >> 16;   // RNE to bf16
  return (unsigned short)u;
}
__device__ __forceinline__ float b2f(unsigned short u) {
  return __uint_as_float(((unsigned)u) << 16);
}

// ================= CSR build (merged across 3 edge sets) =================

__global__ __launch_bounds__(256) void deg_count_all(const int* __restrict__ ea,
                                                     const int* __restrict__ eb,
                                                     const int* __restrict__ ec,
                                                     int* __restrict__ da,
                                                     int* __restrict__ db,
                                                     int* __restrict__ dc) {
  int t = blockIdx.x * 256 + threadIdx.x;
  if (t < EADJ) {
    atomicAdd(&da[ea[EADJ + t]], 1);
  } else if (t < EADJ + EB2C) {
    int e = t - EADJ;
    atomicAdd(&db[eb[EB2C + e]], 1);
  } else if (t < EADJ + EB2C + EC2T) {
    int e = t - EADJ - EB2C;
    atomicAdd(&dc[ec[EC2T + e]], 1);
  }
}

__global__ __launch_bounds__(256) void scan_bsum_all(const int* __restrict__ da,
                                                     const int* __restrict__ db,
                                                     const int* __restrict__ dc,
                                                     int* __restrict__ bs) {
  const int* deg; int N, lb; int* out;
  int b = blockIdx.x;
  if (b < SBA)            { deg = da; N = NB; lb = b;            out = bs; }
  else if (b < SBA + SBB) { deg = db; N = NC; lb = b - SBA;      out = bs + SBA; }
  else                    { deg = dc; N = NT; lb = 0;            out = bs + SBA + SBB; }
  __shared__ int red[256];
  int t = threadIdx.x;
  int base = lb * 2048 + t * 8;
  int s = 0;
  if (base + 8 <= N) {
    int4 a = *(const int4*)(deg + base);
    int4 c = *(const int4*)(deg + base + 4);
    s = a.x + a.y + a.z + a.w + c.x + c.y + c.z + c.w;
  } else {
#pragma unroll
    for (int i = 0; i < 8; i++) { int idx = base + i; if (idx < N) s += deg[idx]; }
  }
  red[t] = s;
  __syncthreads();
  for (int off = 128; off >= 1; off >>= 1) {
    if (t < off) red[t] += red[t + off];
    __syncthreads();
  }
  if (t == 0) out[lb] = red[0];
}

__global__ __launch_bounds__(256) void scan_excl_all(int* __restrict__ bs) {
  int* p; int n;
  if (blockIdx.x == 0)      { p = bs;             n = SBA; }
  else if (blockIdx.x == 1) { p = bs + SBA;       n = SBB; }
  else                      { p = bs + SBA + SBB; n = SBC; }
  __shared__ int sh[256];
  int t = threadIdx.x;
  sh[t] = (t < n) ? p[t] : 0;
  __syncthreads();
  for (int off = 1; off < 256; off <<= 1) {
    int v = (t >= off) ? sh[t - off] : 0;
    __syncthreads();
    sh[t] += v;
    __syncthreads();
  }
  if (t < n) p[t] = (t == 0) ? 0 : sh[t - 1];
}

__global__ __launch_bounds__(256) void scan_write_all(const int* __restrict__ da,
                                                      const int* __restrict__ db,
                                                      const int* __restrict__ dc,
                                                      const int* __restrict__ bs,
                                                      int* __restrict__ rp_a, int* __restrict__ cur_a,
                                                      int* __restrict__ rp_b, int* __restrict__ cur_b,
                                                      int* __restrict__ rp_c, int* __restrict__ cur_c,
                                                      float* __restrict__ dinv) {
  const int* deg; int N, lb; const int* bsum; int* rp; int* cur; bool dodinv = false;
  int b = blockIdx.x;
  if (b < SBA)            { deg = da; N = NB; lb = b;       bsum = bs;             rp = rp_a; cur = cur_a; dodinv = true; }
  else if (b < SBA + SBB) { deg = db; N = NC; lb = b - SBA; bsum = bs + SBA;       rp = rp_b; cur = cur_b; }
  else                    { deg = dc; N = NT; lb = 0;       bsum = bs + SBA + SBB; rp = rp_c; cur = cur_c; }
  __shared__ int sh[256];
  int t = threadIdx.x;
  int base = lb * 2048 + t * 8;
  int d[8]; int s = 0;
#pragma unroll
  for (int i = 0; i < 8; i++) { int idx = base + i; d[i] = (idx < N) ? deg[idx] : 0; s += d[i]; }
  sh[t] = s;
  __syncthreads();
  for (int off = 1; off < 256; off <<= 1) {
    int v = (t >= off) ? sh[t - off] : 0;
    __syncthreads();
    sh[t] += v;
    __syncthreads();
  }
  int run = bsum[lb] + ((t == 0) ? 0 : sh[t - 1]);
#pragma unroll
  for (int i = 0; i < 8; i++) {
    int idx = base + i;
    if (idx < N) {
      rp[idx] = run;
      cur[idx] = run;
      run += d[i];
      if (idx == N - 1) rp[N] = run;
      if (dodinv) dinv[idx] = rsqrtf((float)(d[i] + 1));   // +1 self-loop
    }
  }
}

__global__ __launch_bounds__(256) void csr_fill_all(const int* __restrict__ ea,
                                                    const int* __restrict__ eb,
                                                    const int* __restrict__ ec,
                                                    int* __restrict__ cur_a, int* __restrict__ cur_b, int* __restrict__ cur_c,
                                                    int* __restrict__ col_a, int* __restrict__ col_b, int* __restrict__ col_c) {
  int t = blockIdx.x * 256 + threadIdx.x;
  if (t < EADJ) {
    int src = ea[t], dst = ea[EADJ + t];
    col_a[atomicAdd(&cur_a[dst], 1)] = src;
  } else if (t < EADJ + EB2C) {
    int e = t - EADJ;
    int src = eb[e], dst = eb[EB2C + e];
    col_b[atomicAdd(&cur_b[dst], 1)] = src;
  } else if (t < EADJ + EB2C + EC2T) {
    int e = t - EADJ - EB2C;
    int src = ec[e], dst = ec[EC2T + e];
    col_c[atomicAdd(&cur_c[dst], 1)] = src;
  }
}

// ================= attention-weight folding =================
// wt[mat][k*4+h] = sum_c W[k, h*32+c] * att[h,c]
__global__ __launch_bounds__(256) void prep_watt(const float* __restrict__ W0, const float* __restrict__ A0,
                                                 const float* __restrict__ W1, const float* __restrict__ A1,
                                                 const float* __restrict__ W2, const float* __restrict__ A2,
                                                 const float* __restrict__ W3, const float* __restrict__ A3,
                                                 float* __restrict__ wt) {
  const float* Ws[4] = {W0, W1, W2, W3};
  const float* As[4] = {A0, A1, A2, A3};
  int t = threadIdx.x;
#pragma unroll
  for (int mm = 0; mm < 4; mm++) {
#pragma unroll
    for (int r = 0; r < 2; r++) {
      int idx = r * 256 + t;
      int k = idx >> 2, h = idx & 3;
      float s = 0.f;
      for (int c = 0; c < 32; c++) s += Ws[mm][k * 128 + h * 32 + c] * As[mm][h * 32 + c];
      wt[mm * 512 + k * 4 + h] = s;
    }
  }
}

// Pre-convert weights to bf16 B-operand layout (transposed): bt[n*128+k] = bf16(W[k*128+n]).
// Block 3 builds the two zero-padded w̃ tiles (16x128 each).
__global__ __launch_bounds__(256) void conv_w(const float* __restrict__ W1,
                                              const float* __restrict__ W2,
                                              const float* __restrict__ W3,
                                              const float* __restrict__ wt,
                                              unsigned short* __restrict__ bt1,
                                              unsigned short* __restrict__ bt2,
                                              unsigned short* __restrict__ bt3,
                                              unsigned short* __restrict__ wtb) {
  int b = blockIdx.x, t = threadIdx.x;
  if (b < 3) {
    const float* W = (b == 0) ? W1 : (b == 1) ? W2 : W3;
    unsigned short* bt = (b == 0) ? bt1 : (b == 1) ? bt2 : bt3;
#pragma unroll
    for (int i = 0; i < 16; i++) {
      int flat4 = i * 256 + t;
      int k = flat4 >> 5;
      int n0 = (flat4 & 31) * 4;
      float4 v = *(const float4*)(W + k * 128 + n0);
      bt[(n0 + 0) * 128 + k] = f2b(v.x);
      bt[(n0 + 1) * 128 + k] = f2b(v.y);
      bt[(n0 + 2) * 128 + k] = f2b(v.z);
      bt[(n0 + 3) * 128 + k] = f2b(v.w);
    }
  } else {
#pragma unroll
    for (int i = 0; i < 16; i++) {
      int idx = i * 256 + t;              // seg0 = b2c_src w̃, seg1 = c2t_src w̃
      int seg = idx >> 11, r = idx & 2047;
      int n = r >> 7, k = r & 127;
      const float* ws = wt + seg * 1024;  // wt seg 0 and seg 2
      wtb[seg * 2048 + n * 128 + k] = (n < 4) ? f2b(ws[k * 4 + n]) : (unsigned short)0;
    }
  }
}

// a_d for cable and transformer nodes: one wave per node
__global__ __launch_bounds__(256) void small_ad(const float* __restrict__ x_c,
                                                const float* __restrict__ x_t,
                                                const float* __restrict__ wt,
                                                float* __restrict__ a_d_c,
                                                float* __restrict__ a_d_t) {
  int widx = blockIdx.x * 4 + (threadIdx.x >> 6);
  int lane = threadIdx.x & 63;
  const float* x; const float* w; float* out;
  if (widx < NC)            { x = x_c + (size_t)widx * 128;        w = wt + 512;  out = a_d_c + widx * 4; }
  else if (widx < NC + NT)  { int n = widx - NC; x = x_t + (size_t)n * 128; w = wt + 1536; out = a_d_t + n * 4; }
  else return;
  float2 xv = ((const float2*)x)[lane];
  float p[4];
#pragma unroll
  for (int h = 0; h < 4; h++)
    p[h] = xv.x * w[(2 * lane) * 4 + h] + xv.y * w[(2 * lane + 1) * 4 + h];
#pragma unroll
  for (int off = 32; off >= 1; off >>= 1)
#pragma unroll
    for (int h = 0; h < 4; h++) p[h] += __shfl_xor(p[h], off);
  if (lane == 0) *(float4*)out = (float4){p[0], p[1], p[2], p[3]};
}

// ================= fused GEMMs =================
// B pre-converted bf16 in global (bt*); staged to LDS with conflict-free coalesced
// copies (rows padded to 136 shorts = 272 B, 16B-aligned). A prefetched 8x float4
// per lane BEFORE the barrier for memory-level parallelism; K-loop is pure
// ds_read_b128 + MFMA (no vmcnt in hot loop).
__global__ __launch_bounds__(256, 2) void gemm_dual(const float* __restrict__ X,
                                                    const unsigned short* __restrict__ bt1,
                                                    const unsigned short* __restrict__ bt2,
                                                    const unsigned short* __restrict__ wtb,
                                                    const float* __restrict__ dinv,
                                                    unsigned short* __restrict__ xs_out,
                                                    unsigned short* __restrict__ hg_out,
                                                    float* __restrict__ as_out, int M) {
  __shared__ unsigned short Bs1[128 * 136];
  __shared__ unsigned short Bs2[128 * 136];
  __shared__ unsigned short Wsh[16 * 136];
  const int tid = threadIdx.x;
  const int lane = tid & 63;
  const int wave = tid >> 6;
  const int m = lane & 15, q = lane >> 4;

  int r0 = blockIdx.x * 64 + wave * 16 + m;
  if (r0 >= M) r0 = M - 1;
  const float4* ap = (const float4*)(X + (size_t)r0 * 128);

  // A prefetch: all 8 float4 this lane needs, issued before anything waits
  float4 av[8];
#pragma unroll
  for (int ks = 0; ks < 4; ks++) {
    av[ks * 2]     = ap[ks * 8 + q * 2];
    av[ks * 2 + 1] = ap[ks * 8 + q * 2 + 1];
  }

  // stage B: coalesced 16B copies, no transpose (bt already B-layout)
#pragma unroll
  for (int i = 0; i < 8; i++) {
    int c = i * 256 + tid;
    int row = c >> 4, off = (c & 15) * 8;
    *(s16x8*)(Bs1 + row * 136 + off) = *(const s16x8*)(bt1 + row * 128 + off);
    *(s16x8*)(Bs2 + row * 136 + off) = *(const s16x8*)(bt2 + row * 128 + off);
  }
  {
    int row = tid >> 4, off = (tid & 15) * 8;
    *(s16x8*)(Wsh + row * 136 + off) = *(const s16x8*)(wtb + row * 128 + off);
  }
  __syncthreads();

  // convert A to fragments
  frag_u af[4];
#pragma unroll
  for (int ks = 0; ks < 4; ks++) {
    float4 v0 = av[ks * 2], v1 = av[ks * 2 + 1];
    af[ks].s = (s16x8){(short)f2b(v0.x), (short)f2b(v0.y), (short)f2b(v0.z), (short)f2b(v0.w),
                       (short)f2b(v1.x), (short)f2b(v1.y), (short)f2b(v1.z), (short)f2b(v1.w)};
  }

  f32x4 acc1[8], acc2[8], accw;
  accw = (f32x4){0.f, 0.f, 0.f, 0.f};
#pragma unroll
  for (int ct = 0; ct < 8; ct++) {
    acc1[ct] = (f32x4){0.f, 0.f, 0.f, 0.f};
    acc2[ct] = (f32x4){0.f, 0.f, 0.f, 0.f};
  }

#pragma unroll
  for (int ks = 0; ks < 4; ks++) {
    const int ko = ks * 32 + q * 8;
    frag_u bw;
    bw.s = *(const s16x8*)(Wsh + m * 136 + ko);
    accw = __builtin_amdgcn_mfma_f32_16x16x32_bf16(af[ks].b, bw.b, accw, 0, 0, 0);
#pragma unroll
    for (int ct = 0; ct < 8; ct++) {
      frag_u b1, b2;
      b1.s = *(const s16x8*)(Bs1 + (ct * 16 + m) * 136 + ko);
      b2.s = *(const s16x8*)(Bs2 + (ct * 16 + m) * 136 + ko);
      acc1[ct] = __builtin_amdgcn_mfma_f32_16x16x32_bf16(af[ks].b, b1.b, acc1[ct], 0, 0, 0);
      acc2[ct] = __builtin_amdgcn_mfma_f32_16x16x32_bf16(af[ks].b, b2.b, acc2[ct], 0, 0, 0);
    }
  }

  // C/D layout: col = lane&15 (=m), row = q*4 + reg
#pragma unroll
  for (int i = 0; i < 4; i++) {
    int r = blockIdx.x * 64 + wave * 16 + q * 4 + i;
    if (r < M) {
      float dd = dinv[r];
      unsigned short* xp = xs_out + (size_t)r * 128 + m;
      unsigned short* hp = hg_out + (size_t)r * 128 + m;
#pragma unroll
      for (int ct = 0; ct < 8; ct++) {
        xp[ct * 16] = f2b(acc1[ct][i]);
        hp[ct * 16] = f2b(dd * acc2[ct][i]);
      }
      if (m < 4) as_out[(size_t)r * 4 + m] = accw[i];
    }
  }
}

__global__ __launch_bounds__(256, 2) void gemm_single(const float* __restrict__ X,
                                                      const unsigned short* __restrict__ bt1,
                                                      const unsigned short* __restrict__ wtb,
                                                      unsigned short* __restrict__ xs_out,
                                                      float* __restrict__ as_out, int M) {
  __shared__ unsigned short Bs1[128 * 136];
  __shared__ unsigned short Wsh[16 * 136];
  const int tid = threadIdx.x;
  const int lane = tid & 63;
  const int wave = tid >> 6;
  const int m = lane & 15, q = lane >> 4;

  int r0 = blockIdx.x * 64 + wave * 16 + m;
  if (r0 >= M) r0 = M - 1;
  const float4* ap = (const float4*)(X + (size_t)r0 * 128);

  float4 av[8];
#pragma unroll
  for (int ks = 0; ks < 4; ks++) {
    av[ks * 2]     = ap[ks * 8 + q * 2];
    av[ks * 2 + 1] = ap[ks * 8 + q * 2 + 1];
  }

#pragma unroll
  for (int i = 0; i < 8; i++) {
    int c = i * 256 + tid;
    int row = c >> 4, off = (c & 15) * 8;
    *(s16x8*)(Bs1 + row * 136 + off) = *(const s16x8*)(bt1 + row * 128 + off);
  }
  {
    int row = tid >> 4, off = (tid & 15) * 8;
    *(s16x8*)(Wsh + row * 136 + off) = *(const s16x8*)(wtb + row * 128 + off);
  }
  __syncthreads();

  frag_u af[4];
#pragma unroll
  for (int ks = 0; ks < 4; ks++) {
    float4 v0 = av[ks * 2], v1 = av[ks * 2 + 1];
    af[ks].s = (s16x8){(short)f2b(v0.x), (short)f2b(v0.y), (short)f2b(v0.z), (short)f2b(v0.w),
                       (short)f2b(v1.x), (short)f2b(v1.y), (short)f2b(v1.z), (short)f2b(v1.w)};
  }

  f32x4 acc1[8], accw;
  accw = (f32x4){0.f, 0.f, 0.f, 0.f};
#pragma unroll
  for (int ct = 0; ct < 8; ct++) acc1[ct] = (f32x4){0.f, 0.f, 0.f, 0.f};

#pragma unroll
  for (int ks = 0; ks < 4; ks++) {
    const int ko = ks * 32 + q * 8;
    frag_u bw;
    bw.s = *(const s16x8*)(Wsh + m * 136 + ko);
    accw = __builtin_amdgcn_mfma_f32_16x16x32_bf16(af[ks].b, bw.b, accw, 0, 0, 0);
#pragma unroll
    for (int ct = 0; ct < 8; ct++) {
      frag_u b1;
      b1.s = *(const s16x8*)(Bs1 + (ct * 16 + m) * 136 + ko);
      acc1[ct] = __builtin_amdgcn_mfma_f32_16x16x32_bf16(af[ks].b, b1.b, acc1[ct], 0, 0, 0);
    }
  }

#pragma unroll
  for (int i = 0; i < 4; i++) {
    int r = blockIdx.x * 64 + wave * 16 + q * 4 + i;
    if (r < M) {
      unsigned short* xp = xs_out + (size_t)r * 128 + m;
#pragma unroll
      for (int ct = 0; ct < 8; ct++) xp[ct * 16] = f2b(acc1[ct][i]);
      if (m < 4) as_out[(size_t)r * 4 + m] = accw[i];
    }
  }
}

// ================= gathers =================

__global__ __launch_bounds__(256) void gat_gather(const int* __restrict__ rowptr,
                                                  const int* __restrict__ col,
                                                  const float* __restrict__ a_s,
                                                  const float* __restrict__ a_d,
                                                  const unsigned short* __restrict__ xs,
                                                  const float* __restrict__ xd_in,
                                                  const float* __restrict__ bias,
                                                  float* __restrict__ out, int Nd, float s) {
  int node = blockIdx.x * 8 + (threadIdx.x >> 5);
  if (node >= Nd) return;
  int g = threadIdx.x & 31;
  int c4 = g * 4, h = g >> 3;
  int lo = rowptr[node], hi = rowptr[node + 1];
  float ad = a_d[(size_t)node * 4 + h];
  float4 acc = {0.f, 0.f, 0.f, 0.f};
  float sexp = 0.f;
  int j = lo;
  for (; j + 1 < hi; j += 2) {
    int s0 = col[j], s1 = col[j + 1];
    float l0 = a_s[(size_t)s0 * 4 + h] + ad;
    float l1 = a_s[(size_t)s1 * 4 + h] + ad;
    ushort4 u0 = *(const ushort4*)(xs + (size_t)s0 * 128 + c4);
    ushort4 u1 = *(const ushort4*)(xs + (size_t)s1 * 128 + c4);
    l0 = l0 > 0.f ? l0 : 0.2f * l0;
    l1 = l1 > 0.f ? l1 : 0.2f * l1;
    float w0 = __expf(l0), w1 = __expf(l1);
    sexp += w0 + w1;
    acc.x += w0 * b2f(u0.x) + w1 * b2f(u1.x);
    acc.y += w0 * b2f(u0.y) + w1 * b2f(u1.y);
    acc.z += w0 * b2f(u0.z) + w1 * b2f(u1.z);
    acc.w += w0 * b2f(u0.w) + w1 * b2f(u1.w);
  }
  if (j < hi) {
    int s0 = col[j];
    float l0 = a_s[(size_t)s0 * 4 + h] + ad;
    ushort4 u0 = *(const ushort4*)(xs + (size_t)s0 * 128 + c4);
    l0 = l0 > 0.f ? l0 : 0.2f * l0;
    float w0 = __expf(l0);
    sexp += w0;
    acc.x += w0 * b2f(u0.x);
    acc.y += w0 * b2f(u0.y);
    acc.z += w0 * b2f(u0.z);
    acc.w += w0 * b2f(u0.w);
  }
  float inv = s / (sexp + 1e-16f);
  float4 xd = *(const float4*)(xd_in + (size_t)node * 128 + c4);
  float4 bv = *(const float4*)(bias + c4);
  float4 r = {xd.x + s * bv.x + inv * acc.x, xd.y + s * bv.y + inv * acc.y,
              xd.z + s * bv.z + inv * acc.z, xd.w + s * bv.w + inv * acc.w};
  *(float4*)(out + (size_t)node * 128 + c4) = r;
}

// GCN gather: hgs rows pre-scaled by dinv[src]; self row folded in; unroll x4.
__global__ __launch_bounds__(256) void gcn_gather(const int* __restrict__ rowptr,
                                                  const int* __restrict__ col,
                                                  const unsigned short* __restrict__ hgs,
                                                  const float* __restrict__ dinv,
                                                  const float* __restrict__ x,
                                                  const float* __restrict__ bias,
                                                  float* __restrict__ out, int N, float s) {
  int node = blockIdx.x * 8 + (threadIdx.x >> 5);
  if (node >= N) return;
  int c4 = (threadIdx.x & 31) * 4;
  int lo = rowptr[node], hi = rowptr[node + 1];
  ushort4 su = *(const ushort4*)(hgs + (size_t)node * 128 + c4);
  float4 acc = {b2f(su.x), b2f(su.y), b2f(su.z), b2f(su.w)};
  int j = lo;
  for (; j + 3 < hi; j += 4) {
    int s0 = col[j], s1 = col[j + 1], s2 = col[j + 2], s3 = col[j + 3];
    ushort4 u0 = *(const ushort4*)(hgs + (size_t)s0 * 128 + c4);
    ushort4 u1 = *(const ushort4*)(hgs + (size_t)s1 * 128 + c4);
    ushort4 u2 = *(const ushort4*)(hgs + (size_t)s2 * 128 + c4);
    ushort4 u3 = *(const ushort4*)(hgs + (size_t)s3 * 128 + c4);
    acc.x += (b2f(u0.x) + b2f(u1.x)) + (b2f(u2.x) + b2f(u3.x));
    acc.y += (b2f(u0.y) + b2f(u1.y)) + (b2f(u2.y) + b2f(u3.y));
    acc.z += (b2f(u0.z) + b2f(u1.z)) + (b2f(u2.z) + b2f(u3.z));
    acc.w += (b2f(u0.w) + b2f(u1.w)) + (b2f(u2.w) + b2f(u3.w));
  }
  for (; j < hi; j++) {
    int s0 = col[j];
    ushort4 u0 = *(const ushort4*)(hgs + (size_t)s0 * 128 + c4);
    acc.x += b2f(u0.x); acc.y += b2f(u0.y); acc.z += b2f(u0.z); acc.w += b2f(u0.w);
  }
  float dd = dinv[node];
  float4 xv = *(const float4*)(x + (size_t)node * 128 + c4);
  float4 bv = *(const float4*)(bias + c4);
  float4 r = {xv.x + s * (dd * acc.x + bv.x), xv.y + s * (dd * acc.y + bv.y),
              xv.z + s * (dd * acc.z + bv.z), xv.w + s * (dd * acc.w + bv.w)};
  *(float4*)(out + (size_t)node * 128 + c4) = r;
}

// ================= host =================
extern "C" void kernel_launch(void* const* d_in, const int* in_sizes, int n_in,
                              void* d_out, int out_size, void* d_ws, size_t ws_size,
                              hipStream_t stream) {
  const float* x_b        = (const float*)d_in[0];
  const float* x_c        = (const float*)d_in[1];
  const float* x_t        = (const float*)d_in[2];
  const int*   e_b2c      = (const int*)d_in[3];
  const int*   e_c2t      = (const int*)d_in[4];
  const int*   e_adj      = (const int*)d_in[5];
  const float* W_b2c_src  = (const float*)d_in[6];
  const float* W_b2c_dst  = (const float*)d_in[7];
  const float* att_b2c_s  = (const float*)d_in[8];
  const float* att_b2c_d  = (const float*)d_in[9];
  const float* b_b2c      = (const float*)d_in[10];
  const float* W_c2t_src  = (const float*)d_in[11];
  const float* W_c2t_dst  = (const float*)d_in[12];
  const float* att_c2t_s  = (const float*)d_in[13];
  const float* att_c2t_d  = (const float*)d_in[14];
  const float* b_c2t      = (const float*)d_in[15];
  const float* W_gcn      = (const float*)d_in[16];
  const float* b_gcn      = (const float*)d_in[17];

  float* h_b = (float*)d_out;
  float* h_c = h_b + (size_t)NB * 128;
  float* h_t = h_c + (size_t)NC * 128;

  char* w = (char*)d_ws;
  auto allocu = [&](size_t n) { unsigned short* p = (unsigned short*)w; w += n * 2; return p; };
  auto allocf = [&](size_t n) { float* p = (float*)w; w += n * 4; return p; };
  auto alloci = [&](size_t n) { int* p = (int*)w; w += n * 4; return p; };

  unsigned short* xs_b = allocu((size_t)NB * 128);   // bf16 payloads
  unsigned short* hgs  = allocu((size_t)NB * 128);   // bf16, dinv-pre-scaled
  unsigned short* xs_c = allocu((size_t)NC * 128);
  unsigned short* bt1  = allocu(128 * 128);          // bf16 W_b2c_src^T
  unsigned short* bt2  = allocu(128 * 128);          // bf16 W_gcn^T
  unsigned short* bt3  = allocu(128 * 128);          // bf16 W_c2t_src^T
  unsigned short* wtb  = allocu(2 * 2048);           // two 16x128 w̃ tiles
  float* a_d_c = allocf((size_t)NC * 4);
  float* a_d_t = allocf((size_t)NT * 4);
  float* a_s_b = allocf((size_t)NB * 4);
  float* a_s_c = allocf((size_t)NC * 4);
  float* dinv  = allocf(NB);
  float* wt    = allocf(4 * 512);
  int* deg_a = alloci(NB);   // deg_a..deg_c contiguous for one memset
  int* deg_b = alloci(NC);
  int* deg_c = alloci(NT);
  int* bs    = alloci(64);
  int* rp_a  = alloci(NB + 1);  int* cur_a = alloci(NB);  int* col_a = alloci(EADJ);
  int* rp_b  = alloci(NC + 1);  int* cur_b = alloci(NC);  int* col_b = alloci(EB2C);
  int* rp_c  = alloci(NT + 1);  int* cur_c = alloci(NT);  int* col_c = alloci(EC2T);

  const int ETOT = EADJ + EB2C + EC2T;

  // ---- CSR build (merged) ----
  hipMemsetAsync(deg_a, 0, (size_t)(NB + NC + NT) * sizeof(int), stream);
  deg_count_all<<<(ETOT + 255) / 256, 256, 0, stream>>>(e_adj, e_b2c, e_c2t, deg_a, deg_b, deg_c);
  scan_bsum_all<<<SBA + SBB + SBC, 256, 0, stream>>>(deg_a, deg_b, deg_c, bs);
  scan_excl_all<<<3, 256, 0, stream>>>(bs);
  scan_write_all<<<SBA + SBB + SBC, 256, 0, stream>>>(deg_a, deg_b, deg_c, bs,
                                                      rp_a, cur_a, rp_b, cur_b, rp_c, cur_c, dinv);
  csr_fill_all<<<(ETOT + 255) / 256, 256, 0, stream>>>(e_adj, e_b2c, e_c2t,
                                                       cur_a, cur_b, cur_c, col_a, col_b, col_c);

  // ---- weight prep ----
  prep_watt<<<1, 256, 0, stream>>>(W_b2c_src, att_b2c_s, W_b2c_dst, att_b2c_d,
                                   W_c2t_src, att_c2t_s, W_c2t_dst, att_c2t_d, wt);
  conv_w<<<4, 256, 0, stream>>>(W_b2c_src, W_gcn, W_c2t_src, wt, bt1, bt2, bt3, wtb);
  small_ad<<<(NC + NT + 3) / 4, 256, 0, stream>>>(x_c, x_t, wt, a_d_c, a_d_t);

  // ---- big fused GEMM: x_b -> xs_b, hgs (dinv-scaled), a_s_b ----
  gemm_dual<<<(NB + 63) / 64, 256, 0, stream>>>(x_b, bt1, bt2, wtb, dinv,
                                                xs_b, hgs, a_s_b, NB);

  // ---- stage A: building -> cable_group GAT ----
  gat_gather<<<(NC + 7) / 8, 256, 0, stream>>>(rp_b, col_b, a_s_b, a_d_c,
                                               xs_b, x_c, b_b2c, h_c, NC, 0.5f);

  // ---- stage B: cable_group -> transformer GAT ----
  gemm_single<<<(NC + 63) / 64, 256, 0, stream>>>(h_c, bt3, wtb + 2048, xs_c, a_s_c, NC);
  gat_gather<<<(NT + 7) / 8, 256, 0, stream>>>(rp_c, col_c, a_s_c, a_d_t,
                                               xs_c, x_t, b_c2t, h_t, NT, 0.5f);

  // ---- GCN on building adjacency ----
  gcn_gather<<<(NB + 7) / 8, 256, 0, stream>>>(rp_a, col_a, hgs, dinv, x_b, b_gcn, h_b, NB, 0.2f);
}

// Round 7
// 327.014 us; speedup vs baseline: 1.2649x; 1.1115x over previous
//
#include <hip/hip_runtime.h>

#define NB 100000
#define NC 10000
#define NT 1000
#define EADJ 800000
#define EB2C 100000
#define EC2T 10000

// merged hierarchical scan (tile = 2048)
#define SBA 49   // ceil(NB/2048)
#define SBB 5    // ceil(NC/2048)
#define SBC 1    // ceil(NT/2048)

// adj bucketing: bucket = dst >> 11 (2048 nodes/bucket) -> CSR-contiguous regions
#define NBKT 49
#define BIN_BLOCKS 782          // ceil(EADJ/1024)
#define GEMM_BLOCKS 1563        // ceil(NB/64)
#define SFILL_BLOCKS 430        // ceil((EB2C+EC2T)/256)

typedef __bf16 bf16x8 __attribute__((ext_vector_type(8)));
typedef short  s16x8  __attribute__((ext_vector_type(8)));
typedef float  f32x4  __attribute__((ext_vector_type(4)));

union frag_u { s16x8 s; bf16x8 b; };

__device__ __forceinline__ unsigned short f2b(float f) {
  unsigned u = __float_as_uint(f);
  u = (u + 0x7fffu + ((u >> 16) & 1u)) >> 16;   // RNE to bf16
  return (unsigned short)u;
}
__device__ __forceinline__ float b2f(unsigned short u) {
  return __uint_as_float(((unsigned)u) << 16);
}

// ================= L2: degree count (all 3 sets) + prep_watt =================
__global__ __launch_bounds__(256) void k_deg_prep(const int* __restrict__ ea,
                                                  const int* __restrict__ eb,
                                                  const int* __restrict__ ec,
                                                  int* __restrict__ da, int* __restrict__ db, int* __restrict__ dc,
                                                  const float* __restrict__ W0, const float* __restrict__ A0,
                                                  const float* __restrict__ W1, const float* __restrict__ A1,
                                                  const float* __restrict__ W2, const float* __restrict__ A2,
                                                  const float* __restrict__ W3, const float* __restrict__ A3,
                                                  float* __restrict__ wt) {
  int b = blockIdx.x;
  if (b < 3555) {
    int t = b * 256 + threadIdx.x;
    if (t < EADJ) {
      atomicAdd(&da[ea[EADJ + t]], 1);
    } else if (t < EADJ + EB2C) {
      int e = t - EADJ;
      atomicAdd(&db[eb[EB2C + e]], 1);
    } else if (t < EADJ + EB2C + EC2T) {
      int e = t - EADJ - EB2C;
      atomicAdd(&dc[ec[EC2T + e]], 1);
    }
  } else {
    // prep_watt: wt[mat][k*4+h] = sum_c W[k,h*32+c]*att[h,c]
    const float* Ws[4] = {W0, W1, W2, W3};
    const float* As[4] = {A0, A1, A2, A3};
    int t = threadIdx.x;
#pragma unroll
    for (int mm = 0; mm < 4; mm++) {
#pragma unroll
      for (int r = 0; r < 2; r++) {
        int idx = r * 256 + t;
        int k = idx >> 2, h = idx & 3;
        float s = 0.f;
        for (int c = 0; c < 32; c++) s += Ws[mm][k * 128 + h * 32 + c] * As[mm][h * 32 + c];
        wt[mm * 512 + k * 4 + h] = s;
      }
    }
  }
}

// ================= L3: scan_bsum + conv_w + small_ad =================
__global__ __launch_bounds__(256) void k_scan1(const int* __restrict__ da,
                                               const int* __restrict__ db,
                                               const int* __restrict__ dc,
                                               int* __restrict__ bsb,
                                               const float* __restrict__ Wv1,   // W_b2c_src
                                               const float* __restrict__ Wv2,   // W_gcn
                                               const float* __restrict__ Wv3,   // W_c2t_src
                                               const float* __restrict__ wt,
                                               unsigned short* __restrict__ bt1,
                                               unsigned short* __restrict__ bt2,
                                               unsigned short* __restrict__ bt3,
                                               unsigned short* __restrict__ wtb,
                                               const float* __restrict__ x_c,
                                               const float* __restrict__ x_t,
                                               float* __restrict__ a_d_c,
                                               float* __restrict__ a_d_t) {
  __shared__ int red[256];
  int b = blockIdx.x;
  if (b < SBA + SBB + SBC) {
    const int* deg; int N, lb; int* out;
    if (b < SBA)            { deg = da; N = NB; lb = b;       out = bsb; }
    else if (b < SBA + SBB) { deg = db; N = NC; lb = b - SBA; out = bsb + SBA; }
    else                    { deg = dc; N = NT; lb = 0;       out = bsb + SBA + SBB; }
    int t = threadIdx.x;
    int base = lb * 2048 + t * 8;
    int s = 0;
    if (base + 8 <= N) {
      int4 a = *(const int4*)(deg + base);
      int4 c = *(const int4*)(deg + base + 4);
      s = a.x + a.y + a.z + a.w + c.x + c.y + c.z + c.w;
    } else {
#pragma unroll
      for (int i = 0; i < 8; i++) { int idx = base + i; if (idx < N) s += deg[idx]; }
    }
    red[t] = s;
    __syncthreads();
    for (int off = 128; off >= 1; off >>= 1) {
      if (t < off) red[t] += red[t + off];
      __syncthreads();
    }
    if (t == 0) out[lb] = red[0];
  } else if (b < SBA + SBB + SBC + 4) {
    // conv_w: bf16 transposed weights + zero-padded w-tilde tiles
    int cb = b - (SBA + SBB + SBC), t = threadIdx.x;
    if (cb < 3) {
      const float* W = (cb == 0) ? Wv1 : (cb == 1) ? Wv2 : Wv3;
      unsigned short* bt = (cb == 0) ? bt1 : (cb == 1) ? bt2 : bt3;
#pragma unroll
      for (int i = 0; i < 16; i++) {
        int flat4 = i * 256 + t;
        int k = flat4 >> 5;
        int n0 = (flat4 & 31) * 4;
        float4 v = *(const float4*)(W + k * 128 + n0);
        bt[(n0 + 0) * 128 + k] = f2b(v.x);
        bt[(n0 + 1) * 128 + k] = f2b(v.y);
        bt[(n0 + 2) * 128 + k] = f2b(v.z);
        bt[(n0 + 3) * 128 + k] = f2b(v.w);
      }
    } else {
#pragma unroll
      for (int i = 0; i < 16; i++) {
        int idx = i * 256 + t;
        int seg = idx >> 11, r = idx & 2047;
        int n = r >> 7, k = r & 127;
        const float* ws = wt + seg * 1024;  // wt segs 0 and 2
        wtb[seg * 2048 + n * 128 + k] = (n < 4) ? f2b(ws[k * 4 + n]) : (unsigned short)0;
      }
    }
  } else {
    // small_ad: one wave per node
    int widx = (b - (SBA + SBB + SBC + 4)) * 4 + (threadIdx.x >> 6);
    int lane = threadIdx.x & 63;
    const float* x; const float* w; float* out;
    if (widx < NC)           { x = x_c + (size_t)widx * 128;        w = wt + 512;  out = a_d_c + widx * 4; }
    else if (widx < NC + NT) { int n = widx - NC; x = x_t + (size_t)n * 128; w = wt + 1536; out = a_d_t + n * 4; }
    else return;
    float2 xv = ((const float2*)x)[lane];
    float p[4];
#pragma unroll
    for (int h = 0; h < 4; h++)
      p[h] = xv.x * w[(2 * lane) * 4 + h] + xv.y * w[(2 * lane + 1) * 4 + h];
#pragma unroll
    for (int off = 32; off >= 1; off >>= 1)
#pragma unroll
      for (int h = 0; h < 4; h++) p[h] += __shfl_xor(p[h], off);
    if (lane == 0) *(float4*)out = (float4){p[0], p[1], p[2], p[3]};
  }
}

// ================= L4: exclusive scan of block sums =================
__global__ __launch_bounds__(256) void k_scan2(int* __restrict__ bsb) {
  int* p; int n;
  if (blockIdx.x == 0)      { p = bsb;             n = SBA; }
  else if (blockIdx.x == 1) { p = bsb + SBA;       n = SBB; }
  else                      { p = bsb + SBA + SBB; n = SBC; }
  __shared__ int sh[256];
  int t = threadIdx.x;
  sh[t] = (t < n) ? p[t] : 0;
  __syncthreads();
  for (int off = 1; off < 256; off <<= 1) {
    int v = (t >= off) ? sh[t - off] : 0;
    __syncthreads();
    sh[t] += v;
    __syncthreads();
  }
  if (t < n) p[t] = (t == 0) ? 0 : sh[t - 1];
}

// ================= L5: scan_write (+dinv, +bucket cursors) =================
__global__ __launch_bounds__(256) void k_scan3(const int* __restrict__ da,
                                               const int* __restrict__ db,
                                               const int* __restrict__ dc,
                                               const int* __restrict__ bsb,
                                               int* __restrict__ rp_a, int* __restrict__ cur_a,
                                               int* __restrict__ rp_b, int* __restrict__ cur_b,
                                               int* __restrict__ rp_c, int* __restrict__ cur_c,
                                               float* __restrict__ dinv,
                                               int* __restrict__ gcurA) {
  const int* deg; int N, lb; const int* bsum; int* rp; int* cur; bool seta = false;
  int b = blockIdx.x;
  if (b < SBA)            { deg = da; N = NB; lb = b;       bsum = bsb;             rp = rp_a; cur = cur_a; seta = true; }
  else if (b < SBA + SBB) { deg = db; N = NC; lb = b - SBA; bsum = bsb + SBA;       rp = rp_b; cur = cur_b; }
  else                    { deg = dc; N = NT; lb = 0;       bsum = bsb + SBA + SBB; rp = rp_c; cur = cur_c; }
  __shared__ int sh[256];
  int t = threadIdx.x;
  int base = lb * 2048 + t * 8;
  int d[8]; int s = 0;
#pragma unroll
  for (int i = 0; i < 8; i++) { int idx = base + i; d[i] = (idx < N) ? deg[idx] : 0; s += d[i]; }
  sh[t] = s;
  __syncthreads();
  for (int off = 1; off < 256; off <<= 1) {
    int v = (t >= off) ? sh[t - off] : 0;
    __syncthreads();
    sh[t] += v;
    __syncthreads();
  }
  int run = bsum[lb] + ((t == 0) ? 0 : sh[t - 1]);
  if (seta && t == 0) gcurA[lb] = run;     // = rp_a[lb*2048], bucket write cursor
#pragma unroll
  for (int i = 0; i < 8; i++) {
    int idx = base + i;
    if (idx < N) {
      rp[idx] = run;
      cur[idx] = run;
      run += d[i];
      if (idx == N - 1) rp[N] = run;
      if (seta) dinv[idx] = rsqrtf((float)(d[i] + 1));   // +1 self-loop
    }
  }
}

// ================= L6: gemm_dual + bin_adj + small-set fill =================
// gemm: single shared B buffer, two phases (39KB LDS -> 4 blocks/CU).
__global__ __launch_bounds__(256, 4) void k_stage1(const float* __restrict__ X,
                                                   const unsigned short* __restrict__ bt1,
                                                   const unsigned short* __restrict__ bt2,
                                                   const unsigned short* __restrict__ wtb,
                                                   const float* __restrict__ dinv,
                                                   unsigned short* __restrict__ xs_out,
                                                   unsigned short* __restrict__ hg_out,
                                                   float* __restrict__ as_out,
                                                   const int* __restrict__ ea,
                                                   int* __restrict__ gcurA,
                                                   int2* __restrict__ ebuf,
                                                   const int* __restrict__ eb,
                                                   const int* __restrict__ ec,
                                                   int* __restrict__ cur_b, int* __restrict__ cur_c,
                                                   int* __restrict__ col_b, int* __restrict__ col_c) {
  __shared__ __align__(16) unsigned short smem[128 * 136 + 16 * 136];
  int blk = blockIdx.x;
  const int tid = threadIdx.x;

  if (blk < GEMM_BLOCKS) {
    unsigned short* Bs  = smem;
    unsigned short* Wsh = smem + 128 * 136;
    const int lane = tid & 63;
    const int wave = tid >> 6;
    const int m = lane & 15, q = lane >> 4;

    int r0 = blk * 64 + wave * 16 + m;
    if (r0 >= NB) r0 = NB - 1;
    const float4* ap = (const float4*)(X + (size_t)r0 * 128);

    float4 av[8];
#pragma unroll
    for (int ks = 0; ks < 4; ks++) {
      av[ks * 2]     = ap[ks * 8 + q * 2];
      av[ks * 2 + 1] = ap[ks * 8 + q * 2 + 1];
    }

    // phase 1: stage bt1 + Wsh
#pragma unroll
    for (int i = 0; i < 8; i++) {
      int c = i * 256 + tid;
      int row = c >> 4, off = (c & 15) * 8;
      *(s16x8*)(Bs + row * 136 + off) = *(const s16x8*)(bt1 + row * 128 + off);
    }
    {
      int row = tid >> 4, off = (tid & 15) * 8;
      *(s16x8*)(Wsh + row * 136 + off) = *(const s16x8*)(wtb + row * 128 + off);
    }
    __syncthreads();

    frag_u af[4];
#pragma unroll
    for (int ks = 0; ks < 4; ks++) {
      float4 v0 = av[ks * 2], v1 = av[ks * 2 + 1];
      af[ks].s = (s16x8){(short)f2b(v0.x), (short)f2b(v0.y), (short)f2b(v0.z), (short)f2b(v0.w),
                         (short)f2b(v1.x), (short)f2b(v1.y), (short)f2b(v1.z), (short)f2b(v1.w)};
    }

    f32x4 acc1[8], acc2[8], accw;
    accw = (f32x4){0.f, 0.f, 0.f, 0.f};
#pragma unroll
    for (int ct = 0; ct < 8; ct++) {
      acc1[ct] = (f32x4){0.f, 0.f, 0.f, 0.f};
      acc2[ct] = (f32x4){0.f, 0.f, 0.f, 0.f};
    }

#pragma unroll
    for (int ks = 0; ks < 4; ks++) {
      const int ko = ks * 32 + q * 8;
      frag_u bw;
      bw.s = *(const s16x8*)(Wsh + m * 136 + ko);
      accw = __builtin_amdgcn_mfma_f32_16x16x32_bf16(af[ks].b, bw.b, accw, 0, 0, 0);
#pragma unroll
      for (int ct = 0; ct < 8; ct++) {
        frag_u b1;
        b1.s = *(const s16x8*)(Bs + (ct * 16 + m) * 136 + ko);
        acc1[ct] = __builtin_amdgcn_mfma_f32_16x16x32_bf16(af[ks].b, b1.b, acc1[ct], 0, 0, 0);
      }
    }
    __syncthreads();   // done reading phase-1 B

    // phase 2: stage bt2 into same buffer
#pragma unroll
    for (int i = 0; i < 8; i++) {
      int c = i * 256 + tid;
      int row = c >> 4, off = (c & 15) * 8;
      *(s16x8*)(Bs + row * 136 + off) = *(const s16x8*)(bt2 + row * 128 + off);
    }
    __syncthreads();

#pragma unroll
    for (int ks = 0; ks < 4; ks++) {
      const int ko = ks * 32 + q * 8;
#pragma unroll
      for (int ct = 0; ct < 8; ct++) {
        frag_u b2;
        b2.s = *(const s16x8*)(Bs + (ct * 16 + m) * 136 + ko);
        acc2[ct] = __builtin_amdgcn_mfma_f32_16x16x32_bf16(af[ks].b, b2.b, acc2[ct], 0, 0, 0);
      }
    }

    // C/D: col = m, row = q*4 + reg
#pragma unroll
    for (int i = 0; i < 4; i++) {
      int r = blk * 64 + wave * 16 + q * 4 + i;
      if (r < NB) {
        float dd = dinv[r];
        unsigned short* xp = xs_out + (size_t)r * 128 + m;
        unsigned short* hp = hg_out + (size_t)r * 128 + m;
#pragma unroll
        for (int ct = 0; ct < 8; ct++) {
          xp[ct * 16] = f2b(acc1[ct][i]);
          hp[ct * 16] = f2b(dd * acc2[ct][i]);
        }
        if (m < 4) as_out[(size_t)r * 4 + m] = accw[i];
      }
    }
  } else if (blk < GEMM_BLOCKS + BIN_BLOCKS) {
    // bin_adj: bucket edges by dst>>11 with LDS histogram, bulk-reserved coalesced writes
    int lb = blk - GEMM_BLOCKS;
    int* cnt  = (int*)smem;
    int* base = cnt + NBKT;
    if (tid < NBKT) cnt[tid] = 0;
    __syncthreads();
    int e0 = lb * 1024;
    int n = EADJ - e0; if (n > 1024) n = 1024;
    int idx = tid * 4;
    bool act = idx < n;
    int s[4], d[4], bk[4], rk[4];
    if (act) {
      int4 s4 = *(const int4*)(ea + e0 + idx);
      int4 d4 = *(const int4*)(ea + EADJ + e0 + idx);
      s[0] = s4.x; s[1] = s4.y; s[2] = s4.z; s[3] = s4.w;
      d[0] = d4.x; d[1] = d4.y; d[2] = d4.z; d[3] = d4.w;
#pragma unroll
      for (int i = 0; i < 4; i++) { bk[i] = d[i] >> 11; rk[i] = atomicAdd(&cnt[bk[i]], 1); }
    }
    __syncthreads();
    if (tid < NBKT) base[tid] = atomicAdd(&gcurA[tid], cnt[tid]);
    __syncthreads();
    if (act) {
#pragma unroll
      for (int i = 0; i < 4; i++) ebuf[base[bk[i]] + rk[i]] = make_int2(s[i], d[i]);
    }
  } else {
    // small-set fill (b2c + c2t): plain atomic scatter (small enough)
    int t = (blk - GEMM_BLOCKS - BIN_BLOCKS) * 256 + tid;
    if (t < EB2C) {
      int src = eb[t], dst = eb[EB2C + t];
      col_b[atomicAdd(&cur_b[dst], 1)] = src;
    } else if (t < EB2C + EC2T) {
      int e = t - EB2C;
      int src = ec[e], dst = ec[EC2T + e];
      col_c[atomicAdd(&cur_c[dst], 1)] = src;
    }
  }
}

// ================= L7: fill_adj + gat_gather(NC) =================
__global__ __launch_bounds__(256) void k_stage2(const int* __restrict__ rp_a,
                                                const int2* __restrict__ ebuf,
                                                int* __restrict__ cur_a,
                                                int* __restrict__ col_a,
                                                const int* __restrict__ rp_b,
                                                const int* __restrict__ col_b,
                                                const float* __restrict__ a_s,
                                                const float* __restrict__ a_d,
                                                const unsigned short* __restrict__ xs,
                                                const float* __restrict__ x_c,
                                                const float* __restrict__ bias,
                                                float* __restrict__ h_c) {
  int b = blockIdx.x;
  if (b < 2 * NBKT) {
    // fill_adj: 2 blocks per bucket; writes confined to this bucket's col window
    int bkt = b >> 1;
    int lo = rp_a[bkt * 2048];
    int hiN = (bkt + 1) * 2048; if (hiN > NB) hiN = NB;
    int hi = rp_a[hiN];
    int half = (hi - lo + 1) >> 1;
    int s = lo + (b & 1) * half;
    int e = (b & 1) ? hi : lo + half;
    for (int j = s + threadIdx.x; j < e; j += 256) {
      int2 p = ebuf[j];
      int pos = atomicAdd(&cur_a[p.y], 1);
      col_a[pos] = p.x;
    }
  } else {
    // gat_gather for cable_group
    int node = (b - 2 * NBKT) * 8 + (threadIdx.x >> 5);
    if (node >= NC) return;
    int g = threadIdx.x & 31;
    int c4 = g * 4, h = g >> 3;
    int lo = rp_b[node], hi = rp_b[node + 1];
    float ad = a_d[(size_t)node * 4 + h];
    float4 acc = {0.f, 0.f, 0.f, 0.f};
    float sexp = 0.f;
    int j = lo;
    for (; j + 1 < hi; j += 2) {
      int s0 = col_b[j], s1 = col_b[j + 1];
      float l0 = a_s[(size_t)s0 * 4 + h] + ad;
      float l1 = a_s[(size_t)s1 * 4 + h] + ad;
      ushort4 u0 = *(const ushort4*)(xs + (size_t)s0 * 128 + c4);
      ushort4 u1 = *(const ushort4*)(xs + (size_t)s1 * 128 + c4);
      l0 = l0 > 0.f ? l0 : 0.2f * l0;
      l1 = l1 > 0.f ? l1 : 0.2f * l1;
      float w0 = __expf(l0), w1 = __expf(l1);
      sexp += w0 + w1;
      acc.x += w0 * b2f(u0.x) + w1 * b2f(u1.x);
      acc.y += w0 * b2f(u0.y) + w1 * b2f(u1.y);
      acc.z += w0 * b2f(u0.z) + w1 * b2f(u1.z);
      acc.w += w0 * b2f(u0.w) + w1 * b2f(u1.w);
    }
    if (j < hi) {
      int s0 = col_b[j];
      float l0 = a_s[(size_t)s0 * 4 + h] + ad;
      ushort4 u0 = *(const ushort4*)(xs + (size_t)s0 * 128 + c4);
      l0 = l0 > 0.f ? l0 : 0.2f * l0;
      float w0 = __expf(l0);
      sexp += w0;
      acc.x += w0 * b2f(u0.x); acc.y += w0 * b2f(u0.y);
      acc.z += w0 * b2f(u0.z); acc.w += w0 * b2f(u0.w);
    }
    float inv = 0.5f / (sexp + 1e-16f);
    float4 xd = *(const float4*)(x_c + (size_t)node * 128 + c4);
    float4 bv = *(const float4*)(bias + c4);
    float4 r = {xd.x + 0.5f * bv.x + inv * acc.x, xd.y + 0.5f * bv.y + inv * acc.y,
                xd.z + 0.5f * bv.z + inv * acc.z, xd.w + 0.5f * bv.w + inv * acc.w};
    *(float4*)(h_c + (size_t)node * 128 + c4) = r;
  }
}

// ================= L8: gemm_single (h_c -> xs_c, a_s_c) =================
__global__ __launch_bounds__(256, 2) void gemm_single(const float* __restrict__ X,
                                                      const unsigned short* __restrict__ bt1,
                                                      const unsigned short* __restrict__ wtb,
                                                      unsigned short* __restrict__ xs_out,
                                                      float* __restrict__ as_out, int M) {
  __shared__ unsigned short Bs1[128 * 136];
  __shared__ unsigned short Wsh[16 * 136];
  const int tid = threadIdx.x;
  const int lane = tid & 63;
  const int wave = tid >> 6;
  const int m = lane & 15, q = lane >> 4;

  int r0 = blockIdx.x * 64 + wave * 16 + m;
  if (r0 >= M) r0 = M - 1;
  const float4* ap = (const float4*)(X + (size_t)r0 * 128);

  float4 av[8];
#pragma unroll
  for (int ks = 0; ks < 4; ks++) {
    av[ks * 2]     = ap[ks * 8 + q * 2];
    av[ks * 2 + 1] = ap[ks * 8 + q * 2 + 1];
  }

#pragma unroll
  for (int i = 0; i < 8; i++) {
    int c = i * 256 + tid;
    int row = c >> 4, off = (c & 15) * 8;
    *(s16x8*)(Bs1 + row * 136 + off) = *(const s16x8*)(bt1 + row * 128 + off);
  }
  {
    int row = tid >> 4, off = (tid & 15) * 8;
    *(s16x8*)(Wsh + row * 136 + off) = *(const s16x8*)(wtb + row * 128 + off);
  }
  __syncthreads();

  frag_u af[4];
#pragma unroll
  for (int ks = 0; ks < 4; ks++) {
    float4 v0 = av[ks * 2], v1 = av[ks * 2 + 1];
    af[ks].s = (s16x8){(short)f2b(v0.x), (short)f2b(v0.y), (short)f2b(v0.z), (short)f2b(v0.w),
                       (short)f2b(v1.x), (short)f2b(v1.y), (short)f2b(v1.z), (short)f2b(v1.w)};
  }

  f32x4 acc1[8], accw;
  accw = (f32x4){0.f, 0.f, 0.f, 0.f};
#pragma unroll
  for (int ct = 0; ct < 8; ct++) acc1[ct] = (f32x4){0.f, 0.f, 0.f, 0.f};

#pragma unroll
  for (int ks = 0; ks < 4; ks++) {
    const int ko = ks * 32 + q * 8;
    frag_u bw;
    bw.s = *(const s16x8*)(Wsh + m * 136 + ko);
    accw = __builtin_amdgcn_mfma_f32_16x16x32_bf16(af[ks].b, bw.b, accw, 0, 0, 0);
#pragma unroll
    for (int ct = 0; ct < 8; ct++) {
      frag_u b1;
      b1.s = *(const s16x8*)(Bs1 + (ct * 16 + m) * 136 + ko);
      acc1[ct] = __builtin_amdgcn_mfma_f32_16x16x32_bf16(af[ks].b, b1.b, acc1[ct], 0, 0, 0);
    }
  }

#pragma unroll
  for (int i = 0; i < 4; i++) {
    int r = blockIdx.x * 64 + wave * 16 + q * 4 + i;
    if (r < M) {
      unsigned short* xp = xs_out + (size_t)r * 128 + m;
#pragma unroll
      for (int ct = 0; ct < 8; ct++) xp[ct * 16] = f2b(acc1[ct][i]);
      if (m < 4) as_out[(size_t)r * 4 + m] = accw[i];
    }
  }
}

// ================= L9: gat_gather(NT) + gcn_gather =================
__global__ __launch_bounds__(256) void k_final(const int* __restrict__ rp_c,
                                               const int* __restrict__ col_c,
                                               const float* __restrict__ a_s_c,
                                               const float* __restrict__ a_d_t,
                                               const unsigned short* __restrict__ xs_c,
                                               const float* __restrict__ x_t,
                                               const float* __restrict__ b_c2t,
                                               float* __restrict__ h_t,
                                               const int* __restrict__ rp_a,
                                               const int* __restrict__ col_a,
                                               const unsigned short* __restrict__ hgs,
                                               const float* __restrict__ dinv,
                                               const float* __restrict__ x_b,
                                               const float* __restrict__ b_gcn,
                                               float* __restrict__ h_b) {
  int b = blockIdx.x;
  if (b < 125) {
    // gat_gather for transformer
    int node = b * 8 + (threadIdx.x >> 5);
    if (node >= NT) return;
    int g = threadIdx.x & 31;
    int c4 = g * 4, h = g >> 3;
    int lo = rp_c[node], hi = rp_c[node + 1];
    float ad = a_d_t[(size_t)node * 4 + h];
    float4 acc = {0.f, 0.f, 0.f, 0.f};
    float sexp = 0.f;
    for (int j = lo; j < hi; j++) {
      int s0 = col_c[j];
      float l0 = a_s_c[(size_t)s0 * 4 + h] + ad;
      ushort4 u0 = *(const ushort4*)(xs_c + (size_t)s0 * 128 + c4);
      l0 = l0 > 0.f ? l0 : 0.2f * l0;
      float w0 = __expf(l0);
      sexp += w0;
      acc.x += w0 * b2f(u0.x); acc.y += w0 * b2f(u0.y);
      acc.z += w0 * b2f(u0.z); acc.w += w0 * b2f(u0.w);
    }
    float inv = 0.5f / (sexp + 1e-16f);
    float4 xd = *(const float4*)(x_t + (size_t)node * 128 + c4);
    float4 bv = *(const float4*)(b_c2t + c4);
    float4 r = {xd.x + 0.5f * bv.x + inv * acc.x, xd.y + 0.5f * bv.y + inv * acc.y,
                xd.z + 0.5f * bv.z + inv * acc.z, xd.w + 0.5f * bv.w + inv * acc.w};
    *(float4*)(h_t + (size_t)node * 128 + c4) = r;
  } else {
    // gcn_gather (hgs pre-scaled by dinv[src]; self folded; unroll x4)
    int node = (b - 125) * 8 + (threadIdx.x >> 5);
    if (node >= NB) return;
    int c4 = (threadIdx.x & 31) * 4;
    int lo = rp_a[node], hi = rp_a[node + 1];
    ushort4 su = *(const ushort4*)(hgs + (size_t)node * 128 + c4);
    float4 acc = {b2f(su.x), b2f(su.y), b2f(su.z), b2f(su.w)};
    int j = lo;
    for (; j + 3 < hi; j += 4) {
      int s0 = col_a[j], s1 = col_a[j + 1], s2 = col_a[j + 2], s3 = col_a[j + 3];
      ushort4 u0 = *(const ushort4*)(hgs + (size_t)s0 * 128 + c4);
      ushort4 u1 = *(const ushort4*)(hgs + (size_t)s1 * 128 + c4);
      ushort4 u2 = *(const ushort4*)(hgs + (size_t)s2 * 128 + c4);
      ushort4 u3 = *(const ushort4*)(hgs + (size_t)s3 * 128 + c4);
      acc.x += (b2f(u0.x) + b2f(u1.x)) + (b2f(u2.x) + b2f(u3.x));
      acc.y += (b2f(u0.y) + b2f(u1.y)) + (b2f(u2.y) + b2f(u3.y));
      acc.z += (b2f(u0.z) + b2f(u1.z)) + (b2f(u2.z) + b2f(u3.z));
      acc.w += (b2f(u0.w) + b2f(u1.w)) + (b2f(u2.w) + b2f(u3.w));
    }
    for (; j < hi; j++) {
      int s0 = col_a[j];
      ushort4 u0 = *(const ushort4*)(hgs + (size_t)s0 * 128 + c4);
      acc.x += b2f(u0.x); acc.y += b2f(u0.y); acc.z += b2f(u0.z); acc.w += b2f(u0.w);
    }
    float dd = dinv[node];
    float4 xv = *(const float4*)(x_b + (size_t)node * 128 + c4);
    float4 bv = *(const float4*)(b_gcn + c4);
    float4 r = {xv.x + 0.2f * (dd * acc.x + bv.x), xv.y + 0.2f * (dd * acc.y + bv.y),
                xv.z + 0.2f * (dd * acc.z + bv.z), xv.w + 0.2f * (dd * acc.w + bv.w)};
    *(float4*)(h_b + (size_t)node * 128 + c4) = r;
  }
}

// ================= host =================
extern "C" void kernel_launch(void* const* d_in, const int* in_sizes, int n_in,
                              void* d_out, int out_size, void* d_ws, size_t ws_size,
                              hipStream_t stream) {
  const float* x_b        = (const float*)d_in[0];
  const float* x_c        = (const float*)d_in[1];
  const float* x_t        = (const float*)d_in[2];
  const int*   e_b2c      = (const int*)d_in[3];
  const int*   e_c2t      = (const int*)d_in[4];
  const int*   e_adj      = (const int*)d_in[5];
  const float* W_b2c_src  = (const float*)d_in[6];
  const float* W_b2c_dst  = (const float*)d_in[7];
  const float* att_b2c_s  = (const float*)d_in[8];
  const float* att_b2c_d  = (const float*)d_in[9];
  const float* b_b2c      = (const float*)d_in[10];
  const float* W_c2t_src  = (const float*)d_in[11];
  const float* W_c2t_dst  = (const float*)d_in[12];
  const float* att_c2t_s  = (const float*)d_in[13];
  const float* att_c2t_d  = (const float*)d_in[14];
  const float* b_c2t      = (const float*)d_in[15];
  const float* W_gcn      = (const float*)d_in[16];
  const float* b_gcn      = (const float*)d_in[17];

  float* h_b = (float*)d_out;
  float* h_c = h_b + (size_t)NB * 128;
  float* h_t = h_c + (size_t)NC * 128;

  char* w = (char*)d_ws;
  auto allocu = [&](size_t n) { unsigned short* p = (unsigned short*)w; w += n * 2; return p; };
  auto allocf = [&](size_t n) { float* p = (float*)w; w += n * 4; return p; };
  auto alloci = [&](size_t n) { int* p = (int*)w; w += n * 4; return p; };

  unsigned short* xs_b = allocu((size_t)NB * 128);
  unsigned short* hgs  = allocu((size_t)NB * 128);
  unsigned short* xs_c = allocu((size_t)NC * 128);
  unsigned short* bt1  = allocu(128 * 128);
  unsigned short* bt2  = allocu(128 * 128);
  unsigned short* bt3  = allocu(128 * 128);
  unsigned short* wtb  = allocu(2 * 2048);
  int2* ebuf = (int2*)w; w += (size_t)EADJ * 8;
  float* a_d_c = allocf((size_t)NC * 4);
  float* a_d_t = allocf((size_t)NT * 4);
  float* a_s_b = allocf((size_t)NB * 4);
  float* a_s_c = allocf((size_t)NC * 4);
  float* dinv  = allocf(NB);
  float* wt    = allocf(4 * 512);
  int* deg_a = alloci(NB);   // contiguous for one memset
  int* deg_b = alloci(NC);
  int* deg_c = alloci(NT);
  int* bsb   = alloci(64);
  int* gcurA = alloci(64);
  int* rp_a  = alloci(NB + 1);  int* cur_a = alloci(NB);  int* col_a = alloci(EADJ);
  int* rp_b  = alloci(NC + 1);  int* cur_b = alloci(NC);  int* col_b = alloci(EB2C);
  int* rp_c  = alloci(NT + 1);  int* cur_c = alloci(NT);  int* col_c = alloci(EC2T);

  hipMemsetAsync(deg_a, 0, (size_t)(NB + NC + NT) * sizeof(int), stream);

  k_deg_prep<<<3556, 256, 0, stream>>>(e_adj, e_b2c, e_c2t, deg_a, deg_b, deg_c,
                                       W_b2c_src, att_b2c_s, W_b2c_dst, att_b2c_d,
                                       W_c2t_src, att_c2t_s, W_c2t_dst, att_c2t_d, wt);

  k_scan1<<<SBA + SBB + SBC + 4 + 2750, 256, 0, stream>>>(deg_a, deg_b, deg_c, bsb,
                                                          W_b2c_src, W_gcn, W_c2t_src, wt,
                                                          bt1, bt2, bt3, wtb,
                                                          x_c, x_t, a_d_c, a_d_t);

  k_scan2<<<3, 256, 0, stream>>>(bsb);

  k_scan3<<<SBA + SBB + SBC, 256, 0, stream>>>(deg_a, deg_b, deg_c, bsb,
                                               rp_a, cur_a, rp_b, cur_b, rp_c, cur_c,
                                               dinv, gcurA);

  k_stage1<<<GEMM_BLOCKS + BIN_BLOCKS + SFILL_BLOCKS, 256, 0, stream>>>(
      x_b, bt1, bt2, wtb, dinv, xs_b, hgs, a_s_b,
      e_adj, gcurA, ebuf, e_b2c, e_c2t, cur_b, cur_c, col_b, col_c);

  k_stage2<<<2 * NBKT + 1250, 256, 0, stream>>>(rp_a, ebuf, cur_a, col_a,
                                                rp_b, col_b, a_s_b, a_d_c,
                                                xs_b, x_c, b_b2c, h_c);

  gemm_single<<<(NC + 63) / 64, 256, 0, stream>>>(h_c, bt3, wtb + 2048, xs_c, a_s_c, NC);

  k_final<<<125 + (NB + 7) / 8, 256, 0, stream>>>(rp_c, col_c, a_s_c, a_d_t, xs_c, x_t,
                                                  b_c2t, h_t,
                                                  rp_a, col_a, hgs, dinv, x_b, b_gcn, h_b);
}